// Round 5
// baseline (679.627 us; speedup 1.0000x reference)
//
#include <hip/hip_runtime.h>
#include <hip/hip_fp16.h>

#define N_NODES 100000
#define N_EDGES 1600000
#define K_ITER 10

#define TPN 6    // threads per node (8 features each, one 16B fp16 load)
#define NPB 32   // nodes per block (block = 192 threads = 3 waves)
#define NBIN 256 // degree bins for counting sort

#define SCAN_TB   256
#define SCAN_EPT  8
#define SCAN_SEG  (SCAN_TB * SCAN_EPT)
#define SCAN_NB   ((N_NODES + SCAN_SEG - 1) / SCAN_SEG)   // 49

// ---------------------------------------------------------------------------
// pos_local[e] = cnt[row[e]]++   (rank of edge within its destination row)
__global__ void k_count(const int* __restrict__ row, int* __restrict__ cnt,
                        int* __restrict__ pos_local, int E) {
    int i = blockIdx.x * blockDim.x + threadIdx.x;
    if (i < E) pos_local[i] = atomicAdd(&cnt[row[i]], 1);
}

// Degree histogram (LDS-privatized)
__global__ void k_hist(const int* __restrict__ cnt, int* __restrict__ hist, int n) {
    __shared__ int lh[NBIN];
    for (int j = threadIdx.x; j < NBIN; j += blockDim.x) lh[j] = 0;
    __syncthreads();
    int i = blockIdx.x * blockDim.x + threadIdx.x;
    if (i < n) atomicAdd(&lh[min(cnt[i], NBIN - 1)], 1);
    __syncthreads();
    for (int j = threadIdx.x; j < NBIN; j += blockDim.x)
        if (lh[j]) atomicAdd(&hist[j], lh[j]);
}

// Exclusive scan of 256 bins -> bincur (cursor start per bin)
__global__ void k_hscan(const int* __restrict__ hist, int* __restrict__ bincur) {
    __shared__ int sh[NBIN];
    int t = threadIdx.x;
    int v0 = hist[t];
    sh[t] = v0;
    __syncthreads();
    for (int off = 1; off < NBIN; off <<= 1) {
        int v = (t >= off) ? sh[t - off] : 0;
        __syncthreads();
        sh[t] += v;
        __syncthreads();
    }
    bincur[t] = sh[t] - v0;
}

// Assign sorted positions: perm[s]=node, inv[node]=s (block-privatized ranking)
__global__ void k_perm(const int* __restrict__ cnt, int* __restrict__ bincur,
                       int* __restrict__ perm, int* __restrict__ inv, int n) {
    __shared__ int lh[NBIN], lbase[NBIN], lcur[NBIN];
    for (int j = threadIdx.x; j < NBIN; j += blockDim.x) { lh[j] = 0; lcur[j] = 0; }
    __syncthreads();
    int i = blockIdx.x * blockDim.x + threadIdx.x;
    int d = -1;
    if (i < n) { d = min(cnt[i], NBIN - 1); atomicAdd(&lh[d], 1); }
    __syncthreads();
    for (int j = threadIdx.x; j < NBIN; j += blockDim.x)
        if (lh[j]) lbase[j] = atomicAdd(&bincur[j], lh[j]);
    __syncthreads();
    if (i < n) {
        int lr = atomicAdd(&lcur[d], 1);
        int s = lbase[d] + lr;
        perm[s] = i;
        inv[i] = s;
    }
}

// Scan over SORTED degree sequence cnt[perm[s]] -> rowptr (sorted domain)
__global__ void k_scanA(const int* __restrict__ cnt, const int* __restrict__ perm,
                        int* __restrict__ thread_off, int* __restrict__ blocksum) {
    __shared__ int sh[SCAN_TB];
    int b = blockIdx.x, t = threadIdx.x;
    int base = b * SCAN_SEG + t * SCAN_EPT;
    int s = 0;
#pragma unroll
    for (int j = 0; j < SCAN_EPT; ++j) {
        int i = base + j;
        if (i < N_NODES) s += cnt[perm[i]];
    }
    sh[t] = s;
    __syncthreads();
    for (int off = 1; off < SCAN_TB; off <<= 1) {
        int v = (t >= off) ? sh[t - off] : 0;
        __syncthreads();
        sh[t] += v;
        __syncthreads();
    }
    thread_off[b * SCAN_TB + t] = sh[t] - s;
    if (t == SCAN_TB - 1) blocksum[b] = sh[t];
}

__global__ void k_scanB(const int* __restrict__ blocksum, int* __restrict__ blockoff,
                        int* __restrict__ rowptr) {
    if (threadIdx.x == 0) {
        int run = 0;
        for (int b = 0; b < SCAN_NB; ++b) {
            blockoff[b] = run;
            run += blocksum[b];
        }
        rowptr[N_NODES] = run;
    }
}

__global__ void k_scanC(const int* __restrict__ cnt, const int* __restrict__ perm,
                        const int* __restrict__ thread_off,
                        const int* __restrict__ blockoff, int* __restrict__ rowptr) {
    int b = blockIdx.x, t = threadIdx.x;
    int base = b * SCAN_SEG + t * SCAN_EPT;
    int run = blockoff[b] + thread_off[b * SCAN_TB + t];
#pragma unroll
    for (int j = 0; j < SCAN_EPT; ++j) {
        int i = base + j;
        if (i < N_NODES) {
            rowptr[i] = run;
            run += cnt[perm[i]];
        }
    }
}

// Atomic-free fill in sorted domain: epack[rowptr[inv[r]]+pos_local] = {inv[col]*TPN, w}
__global__ void k_fill(const int* __restrict__ row, const int* __restrict__ col,
                       const float* __restrict__ w, const int* __restrict__ rowptr,
                       const int* __restrict__ inv, const int* __restrict__ pos_local,
                       int2* __restrict__ epack, int E) {
    int i = blockIdx.x * blockDim.x + threadIdx.x;
    if (i < E) {
        int pos = rowptr[inv[row[i]]] + pos_local[i];
        epack[pos] = make_int2(inv[col[i]] * TPN, __float_as_int(w[i]));
    }
}

// scale[s] = 0.9 / (sum_e w + 1e-10), segmented over sorted CSR
__global__ void k_scale(const int* __restrict__ rowptr, const int2* __restrict__ epack,
                        float* __restrict__ scale) {
    int s = blockIdx.x * blockDim.x + threadIdx.x;
    if (s >= N_NODES) return;
    int beg = rowptr[s], end = rowptr[s + 1];
    float sum = 0.f;
    for (int e = beg; e < end; ++e) sum += __int_as_float(epack[e].y);
    scale[s] = 0.9f / (sum + 1e-10f);
}

// x16[s*6+c] = fp16 of x[perm[s]] chunk c (8 floats -> 8 halves, 16B)
__global__ void k_x2h(const float4* __restrict__ x, const int* __restrict__ perm,
                      float4* __restrict__ x16) {
    int s = blockIdx.x * NPB + threadIdx.x / TPN;
    int c = threadIdx.x % TPN;
    if (s >= N_NODES) return;
    int xo = perm[s] * 12 + 2 * c;
    float4 a = x[xo], b = x[xo + 1];
    float4 o;
    ((__half2*)&o)[0] = __floats2half2_rn(a.x, a.y);
    ((__half2*)&o)[1] = __floats2half2_rn(a.z, a.w);
    ((__half2*)&o)[2] = __floats2half2_rn(b.x, b.y);
    ((__half2*)&o)[3] = __floats2half2_rn(b.z, b.w);
    x16[s * TPN + c] = o;
}

__device__ __forceinline__ void unp8(float4 h, float4& a, float4& b) {
    const __half2* hp = (const __half2*)&h;
    float2 t0 = __half22float2(hp[0]), t1 = __half22float2(hp[1]);
    float2 t2 = __half22float2(hp[2]), t3 = __half22float2(hp[3]);
    a = make_float4(t0.x, t0.y, t1.x, t1.y);
    b = make_float4(t2.x, t2.y, t3.x, t3.y);
}

// One pull iteration in sorted domain. dst = 0.1*x[perm[s]] + sum w*scale*h[src]
__global__ void k_pull16(const int* __restrict__ rowptr, const int2* __restrict__ epack,
                         const float* __restrict__ scale, const int* __restrict__ perm,
                         const float4* __restrict__ xf, const float4* __restrict__ src16,
                         float4* __restrict__ dst16) {
    int s = blockIdx.x * NPB + threadIdx.x / TPN;
    int c = threadIdx.x % TPN;
    if (s >= N_NODES) return;
    int beg = rowptr[s], end = rowptr[s + 1];
    float sc = scale[s];
    int xo = perm[s] * 12 + 2 * c;
    float4 xa = xf[xo], xb = xf[xo + 1];
    float4 A0 = make_float4(0.1f * xa.x, 0.1f * xa.y, 0.1f * xa.z, 0.1f * xa.w);
    float4 B0 = make_float4(0.1f * xb.x, 0.1f * xb.y, 0.1f * xb.z, 0.1f * xb.w);
    float4 A1 = make_float4(0, 0, 0, 0), B1 = make_float4(0, 0, 0, 0);
    float4 A2 = make_float4(0, 0, 0, 0), B2 = make_float4(0, 0, 0, 0);
    float4 A3 = make_float4(0, 0, 0, 0), B3 = make_float4(0, 0, 0, 0);
    int e = beg;
    for (; e + 4 <= end; e += 4) {
        int2 p0 = epack[e], p1 = epack[e + 1], p2 = epack[e + 2], p3 = epack[e + 3];
        float4 h0 = src16[p0.x + c], h1 = src16[p1.x + c];
        float4 h2 = src16[p2.x + c], h3 = src16[p3.x + c];
        float n0 = __int_as_float(p0.y) * sc, n1 = __int_as_float(p1.y) * sc;
        float n2 = __int_as_float(p2.y) * sc, n3 = __int_as_float(p3.y) * sc;
        float4 fa, fb;
        unp8(h0, fa, fb);
        A0.x += n0 * fa.x; A0.y += n0 * fa.y; A0.z += n0 * fa.z; A0.w += n0 * fa.w;
        B0.x += n0 * fb.x; B0.y += n0 * fb.y; B0.z += n0 * fb.z; B0.w += n0 * fb.w;
        unp8(h1, fa, fb);
        A1.x += n1 * fa.x; A1.y += n1 * fa.y; A1.z += n1 * fa.z; A1.w += n1 * fa.w;
        B1.x += n1 * fb.x; B1.y += n1 * fb.y; B1.z += n1 * fb.z; B1.w += n1 * fb.w;
        unp8(h2, fa, fb);
        A2.x += n2 * fa.x; A2.y += n2 * fa.y; A2.z += n2 * fa.z; A2.w += n2 * fa.w;
        B2.x += n2 * fb.x; B2.y += n2 * fb.y; B2.z += n2 * fb.z; B2.w += n2 * fb.w;
        unp8(h3, fa, fb);
        A3.x += n3 * fa.x; A3.y += n3 * fa.y; A3.z += n3 * fa.z; A3.w += n3 * fa.w;
        B3.x += n3 * fb.x; B3.y += n3 * fb.y; B3.z += n3 * fb.z; B3.w += n3 * fb.w;
    }
    for (; e < end; ++e) {
        int2 p = epack[e];
        float4 hv = src16[p.x + c];
        float nv = __int_as_float(p.y) * sc;
        float4 fa, fb;
        unp8(hv, fa, fb);
        A0.x += nv * fa.x; A0.y += nv * fa.y; A0.z += nv * fa.z; A0.w += nv * fa.w;
        B0.x += nv * fb.x; B0.y += nv * fb.y; B0.z += nv * fb.z; B0.w += nv * fb.w;
    }
    float4 RA = make_float4(A0.x + A1.x + A2.x + A3.x, A0.y + A1.y + A2.y + A3.y,
                            A0.z + A1.z + A2.z + A3.z, A0.w + A1.w + A2.w + A3.w);
    float4 RB = make_float4(B0.x + B1.x + B2.x + B3.x, B0.y + B1.y + B2.y + B3.y,
                            B0.z + B1.z + B2.z + B3.z, B0.w + B1.w + B2.w + B3.w);
    float4 o;
    ((__half2*)&o)[0] = __floats2half2_rn(RA.x, RA.y);
    ((__half2*)&o)[1] = __floats2half2_rn(RA.z, RA.w);
    ((__half2*)&o)[2] = __floats2half2_rn(RB.x, RB.y);
    ((__half2*)&o)[3] = __floats2half2_rn(RB.z, RB.w);
    dst16[s * TPN + c] = o;
}

// Final iteration: fp32 output, scattered back to original node order via perm
__global__ void k_pull_last(const int* __restrict__ rowptr, const int2* __restrict__ epack,
                            const float* __restrict__ scale, const int* __restrict__ perm,
                            const float4* __restrict__ xf, const float4* __restrict__ src16,
                            float4* __restrict__ out) {
    int s = blockIdx.x * NPB + threadIdx.x / TPN;
    int c = threadIdx.x % TPN;
    if (s >= N_NODES) return;
    int beg = rowptr[s], end = rowptr[s + 1];
    float sc = scale[s];
    int xo = perm[s] * 12 + 2 * c;
    float4 xa = xf[xo], xb = xf[xo + 1];
    float4 A0 = make_float4(0.1f * xa.x, 0.1f * xa.y, 0.1f * xa.z, 0.1f * xa.w);
    float4 B0 = make_float4(0.1f * xb.x, 0.1f * xb.y, 0.1f * xb.z, 0.1f * xb.w);
    float4 A1 = make_float4(0, 0, 0, 0), B1 = make_float4(0, 0, 0, 0);
    float4 A2 = make_float4(0, 0, 0, 0), B2 = make_float4(0, 0, 0, 0);
    float4 A3 = make_float4(0, 0, 0, 0), B3 = make_float4(0, 0, 0, 0);
    int e = beg;
    for (; e + 4 <= end; e += 4) {
        int2 p0 = epack[e], p1 = epack[e + 1], p2 = epack[e + 2], p3 = epack[e + 3];
        float4 h0 = src16[p0.x + c], h1 = src16[p1.x + c];
        float4 h2 = src16[p2.x + c], h3 = src16[p3.x + c];
        float n0 = __int_as_float(p0.y) * sc, n1 = __int_as_float(p1.y) * sc;
        float n2 = __int_as_float(p2.y) * sc, n3 = __int_as_float(p3.y) * sc;
        float4 fa, fb;
        unp8(h0, fa, fb);
        A0.x += n0 * fa.x; A0.y += n0 * fa.y; A0.z += n0 * fa.z; A0.w += n0 * fa.w;
        B0.x += n0 * fb.x; B0.y += n0 * fb.y; B0.z += n0 * fb.z; B0.w += n0 * fb.w;
        unp8(h1, fa, fb);
        A1.x += n1 * fa.x; A1.y += n1 * fa.y; A1.z += n1 * fa.z; A1.w += n1 * fa.w;
        B1.x += n1 * fb.x; B1.y += n1 * fb.y; B1.z += n1 * fb.z; B1.w += n1 * fb.w;
        unp8(h2, fa, fb);
        A2.x += n2 * fa.x; A2.y += n2 * fa.y; A2.z += n2 * fa.z; A2.w += n2 * fa.w;
        B2.x += n2 * fb.x; B2.y += n2 * fb.y; B2.z += n2 * fb.z; B2.w += n2 * fb.w;
        unp8(h3, fa, fb);
        A3.x += n3 * fa.x; A3.y += n3 * fa.y; A3.z += n3 * fa.z; A3.w += n3 * fa.w;
        B3.x += n3 * fb.x; B3.y += n3 * fb.y; B3.z += n3 * fb.z; B3.w += n3 * fb.w;
    }
    for (; e < end; ++e) {
        int2 p = epack[e];
        float4 hv = src16[p.x + c];
        float nv = __int_as_float(p.y) * sc;
        float4 fa, fb;
        unp8(hv, fa, fb);
        A0.x += nv * fa.x; A0.y += nv * fa.y; A0.z += nv * fa.z; A0.w += nv * fa.w;
        B0.x += nv * fb.x; B0.y += nv * fb.y; B0.z += nv * fb.z; B0.w += nv * fb.w;
    }
    out[xo]     = make_float4(A0.x + A1.x + A2.x + A3.x, A0.y + A1.y + A2.y + A3.y,
                              A0.z + A1.z + A2.z + A3.z, A0.w + A1.w + A2.w + A3.w);
    out[xo + 1] = make_float4(B0.x + B1.x + B2.x + B3.x, B0.y + B1.y + B2.y + B3.y,
                              B0.z + B1.z + B2.z + B3.z, B0.w + B1.w + B2.w + B3.w);
}

extern "C" void kernel_launch(void* const* d_in, const int* in_sizes, int n_in,
                              void* d_out, int out_size, void* d_ws, size_t ws_size,
                              hipStream_t stream) {
    const float* x  = (const float*)d_in[0];
    const int*   ei = (const int*)d_in[1];
    const float* w  = (const float*)d_in[2];
    const int E = in_sizes[2];
    const int* row = ei;        // destination (segment id)
    const int* col = ei + E;    // message source

    // Workspace layout (16B-aligned offsets), peak ~34.1 MB:
    //   rowptr     @ 0           int[N+1]      -> 400,016
    //   epack      @ 400,016     int2[E]       -> 13,200,016
    //   perm       @ 13,200,016  int[N]        -> 13,600,016
    //   inv        @ 13,600,016  int[N]        -> 14,000,016
    //   cnt        @ 14,000,016  int[N]        -> 14,400,016
    //   hist       @ 14,400,016  int[256]      -> 14,401,040
    //   bincur     @ 14,401,040  int[256]      -> 14,402,064
    //   thread_off @ 14,402,064  int[49*256]   -> 14,452,240
    //   blocksum   @ 14,452,240  int[49]       -> 14,452,448 (pad)
    //   blockoff   @ 14,452,448  int[49]       -> 14,452,656 (pad)
    //   scale      @ 14,452,656  float[N]      -> 14,852,656
    //   pos_local  @ 14,852,656  int[E]        -> 21,252,656  [dead after k_fill]
    //   x16        @ 14,852,656  half[N*48]    -> 24,452,656  [aliases pos_local; written after fill]
    //   hA16       @ 24,452,656  half[N*48]    -> 34,052,656
    char* ws = (char*)d_ws;
    int*    rowptr     = (int*)(ws);
    int2*   epack      = (int2*)(ws + 400016);
    int*    perm       = (int*)(ws + 13200016);
    int*    inv        = (int*)(ws + 13600016);
    int*    cnt        = (int*)(ws + 14000016);
    int*    hist       = (int*)(ws + 14400016);
    int*    bincur     = (int*)(ws + 14401040);
    int*    thread_off = (int*)(ws + 14402064);
    int*    blocksum   = (int*)(ws + 14452240);
    int*    blockoff   = (int*)(ws + 14452448);
    float*  scale      = (float*)(ws + 14452656);
    int*    pos_local  = (int*)(ws + 14852656);
    float4* x16        = (float4*)(ws + 14852656);
    float4* hA16       = (float4*)(ws + 24452656);
    float4* out        = (float4*)d_out;

    const int B = 256;
    const int egrid = (E + B - 1) / B;
    const int ngrid = (N_NODES + B - 1) / B;
    const int pgrid = (N_NODES + NPB - 1) / NPB;

    hipMemsetAsync(cnt, 0, N_NODES * sizeof(int), stream);
    hipMemsetAsync(hist, 0, NBIN * sizeof(int), stream);
    k_count<<<egrid, B, 0, stream>>>(row, cnt, pos_local, E);
    k_hist <<<ngrid, B, 0, stream>>>(cnt, hist, N_NODES);
    k_hscan<<<1, NBIN, 0, stream>>>(hist, bincur);
    k_perm <<<ngrid, B, 0, stream>>>(cnt, bincur, perm, inv, N_NODES);
    k_scanA<<<SCAN_NB, SCAN_TB, 0, stream>>>(cnt, perm, thread_off, blocksum);
    k_scanB<<<1, 64, 0, stream>>>(blocksum, blockoff, rowptr);
    k_scanC<<<SCAN_NB, SCAN_TB, 0, stream>>>(cnt, perm, thread_off, blockoff, rowptr);
    k_fill <<<egrid, B, 0, stream>>>(row, col, w, rowptr, inv, pos_local, epack, E);
    k_scale<<<ngrid, B, 0, stream>>>(rowptr, epack, scale);
    k_x2h  <<<pgrid, NPB * TPN, 0, stream>>>((const float4*)x, perm, x16);

    // iters 1..9 ping-pong x16 <-> hA16 (x16 safe to overwrite from iter 2:
    // the alpha-term reads pristine fp32 x each iteration); iter 10 -> d_out
    float4* src = x16;
    float4* dst = hA16;
    for (int k = 1; k <= K_ITER - 1; ++k) {
        k_pull16<<<pgrid, NPB * TPN, 0, stream>>>(rowptr, epack, scale, perm,
                                                  (const float4*)x, src, dst);
        float4* t = src; src = dst; dst = t;
    }
    k_pull_last<<<pgrid, NPB * TPN, 0, stream>>>(rowptr, epack, scale, perm,
                                                 (const float4*)x, src, out);
}